// Round 1
// baseline (3821.643 us; speedup 1.0000x reference)
//
#include <hip/hip_runtime.h>

typedef unsigned short u16;
typedef __bf16 bf16x8 __attribute__((ext_vector_type(8)));
typedef float f32x4 __attribute__((ext_vector_type(4)));

#define Bsz 64
#define Ssz 64
#define Tsz 32
#define Hsz 512
#define Vsz 32000

static __device__ inline u16 f2bf(float f) {
    union { float f; unsigned u; } v; v.f = f;
    unsigned u = v.u;
    unsigned r = (u + 0x7FFFu + ((u >> 16) & 1u)) >> 16;
    return (u16)r;
}

// ---------------- generic f32 -> bf16 convert ----------------
__global__ void convert_kernel(const float* __restrict__ src, u16* __restrict__ dst, int n) {
    for (int i = blockIdx.x * blockDim.x + threadIdx.x; i < n; i += gridDim.x * blockDim.x)
        dst[i] = f2bf(src[i]);
}

// ---------------- embedding gather (bf16 out, (T,B,H) layout) ----------------
__global__ void embed_kernel(const int* __restrict__ target, const float* __restrict__ emb,
                             u16* __restrict__ embbf) {
    int n = Tsz * Bsz * Hsz;
    for (int i = blockIdx.x * blockDim.x + threadIdx.x; i < n; i += gridDim.x * blockDim.x) {
        int t = i / (Bsz * Hsz);
        int rem = i % (Bsz * Hsz);
        int b = rem / Hsz, k = rem % Hsz;
        int id = (t == 0) ? 0 : target[b * Tsz + (t - 1)];
        embbf[i] = f2bf(emb[(size_t)id * Hsz + k]);
    }
}

// ---------------- h0 init: f32 copy + bf16 ----------------
__global__ void h0_kernel(const float* __restrict__ ehid, float* __restrict__ hseq0,
                          u16* __restrict__ h0bf) {
    int i = blockIdx.x * blockDim.x + threadIdx.x;
    if (i < Bsz * Hsz) {
        float f = ehid[i];
        hseq0[i] = f;
        h0bf[i] = f2bf(f);
    }
}

// ---------------- bf16 MFMA GEMM:  C[m][n] = sum_k A[m][k]*Bw[n][k] + bias[n] ----------------
// MODE 0: out[m*N+n]      (Ua_keys)
// MODE 1: out[((m&63)*T + (m>>6))*V + n]   (logits, A rows ordered (t,b))
template <int MODE>
__global__ __launch_bounds__(256) void gemm_bt(const u16* __restrict__ A, const u16* __restrict__ Bw,
                                               const float* __restrict__ bias, float* __restrict__ out,
                                               int M, int N, int K) {
    __shared__ __align__(16) u16 As[128 * 32];
    __shared__ __align__(16) u16 Bs[128 * 32];
    int m0 = blockIdx.x * 128, n0 = blockIdx.y * 128;
    int tid = threadIdx.x, lane = tid & 63, wid = tid >> 6;
    int wm = wid & 1, wn = wid >> 1;
    f32x4 acc[4][4] = {};
    for (int k0 = 0; k0 < K; k0 += 32) {
        for (int i = tid; i < 512; i += 256) {
            int r = i >> 2, c8 = (i & 3) * 8;
            *(uint4*)&As[r * 32 + c8] = *(const uint4*)&A[(size_t)(m0 + r) * K + k0 + c8];
            *(uint4*)&Bs[r * 32 + c8] = *(const uint4*)&Bw[(size_t)(n0 + r) * K + k0 + c8];
        }
        __syncthreads();
        bf16x8 av[4], bvv[4];
        for (int mi = 0; mi < 4; ++mi)
            av[mi] = *(const bf16x8*)&As[(wm * 64 + mi * 16 + (lane & 15)) * 32 + (lane >> 4) * 8];
        for (int ni = 0; ni < 4; ++ni)
            bvv[ni] = *(const bf16x8*)&Bs[(wn * 64 + ni * 16 + (lane & 15)) * 32 + (lane >> 4) * 8];
        for (int mi = 0; mi < 4; ++mi)
            for (int ni = 0; ni < 4; ++ni)
                acc[mi][ni] = __builtin_amdgcn_mfma_f32_16x16x32_bf16(av[mi], bvv[ni], acc[mi][ni], 0, 0, 0);
        __syncthreads();
    }
    for (int mi = 0; mi < 4; ++mi)
        for (int ni = 0; ni < 4; ++ni) {
            int n = n0 + wn * 64 + ni * 16 + (lane & 15);
            float bb = bias[n];
            for (int r = 0; r < 4; ++r) {
                int m = m0 + wm * 64 + mi * 16 + (lane >> 4) * 4 + r;
                float val = acc[mi][ni][r] + bb;
                if (MODE == 0)
                    out[(size_t)m * N + n] = val;
                else {
                    int t = m >> 6, b = m & 63;
                    out[((size_t)(b * Tsz + t)) * Vsz + n] = val;
                }
            }
        }
}

// ---------------- per-step attention (fp32), one block per batch element ----------------
__global__ __launch_bounds__(512) void attn_step(const float* __restrict__ h,   // B x H  (h_seq[t])
                                                 const float* __restrict__ Wa, const float* __restrict__ ba,
                                                 const float* __restrict__ uak, // B x S x H
                                                 const float* __restrict__ va, const float* __restrict__ bv,
                                                 const float* __restrict__ enc, // B x S x H
                                                 u16* __restrict__ ctxbf,       // B x H (bf16)
                                                 float* __restrict__ att,       // d_out attn base
                                                 int t) {
    int b = blockIdx.x;
    int tid = threadIdx.x;
    __shared__ float hs[Hsz];
    __shared__ float whs[Hsz];
    __shared__ float sc[Ssz];
    hs[tid] = h[(size_t)b * Hsz + tid];
    __syncthreads();
    // Wh = h @ Wa.T + ba   (thread tid -> output j=tid)
    {
        float a = ba[tid];
        const float4* wrow = (const float4*)(Wa + (size_t)tid * Hsz);
        const float4* hv4 = (const float4*)hs;
        for (int k4 = 0; k4 < Hsz / 4; ++k4) {
            float4 wv = wrow[k4];
            float4 xv = hv4[k4];
            a += wv.x * xv.x + wv.y * xv.y + wv.z * xv.z + wv.w * xv.w;
        }
        whs[tid] = a;
    }
    __syncthreads();
    int wid = tid >> 6, lane = tid & 63;
    const float* uakb = uak + ((size_t)b * Ssz) * Hsz;
    float bvv = bv[0];
    for (int si = 0; si < 8; ++si) {
        int s = wid * 8 + si;
        const float* urow = uakb + (size_t)s * Hsz;
        float a = 0.f;
        for (int j = lane; j < Hsz; j += 64)
            a += tanhf(whs[j] + urow[j]) * va[j];
        for (int off = 32; off; off >>= 1) a += __shfl_down(a, off);
        if (lane == 0) sc[s] = a + bvv;
    }
    __syncthreads();
    if (wid == 0) {
        float x = sc[lane];
        float mx = x;
        for (int off = 32; off; off >>= 1) mx = fmaxf(mx, __shfl_xor(mx, off));
        float e = __expf(x - mx);
        float sum = e;
        for (int off = 32; off; off >>= 1) sum += __shfl_xor(sum, off);
        float at = e / sum;
        sc[lane] = at;
        att[((size_t)b * Tsz + t) * Ssz + lane] = at;
    }
    __syncthreads();
    // context
    float c = 0.f;
    const float* encb = enc + ((size_t)b * Ssz) * Hsz;
    for (int s = 0; s < Ssz; ++s) c += sc[s] * encb[(size_t)s * Hsz + tid];
    ctxbf[(size_t)b * Hsz + tid] = f2bf(c);
}

// ---------------- per-step GRU via bf16 MFMA, fused gate epilogue ----------------
// grid 8 blocks (j-tiles of 64), 256 threads (4 waves, 2x2 of 32x32)
__global__ __launch_bounds__(256) void gru_step(const u16* __restrict__ embbf_t, // 64x512
                                                const u16* __restrict__ ctxbf,   // 64x512
                                                const u16* __restrict__ hbfp,    // 64x512
                                                const u16* __restrict__ wih,     // 1536x1024
                                                const u16* __restrict__ whh,     // 1536x512
                                                const float* __restrict__ b_ih, const float* __restrict__ b_hh,
                                                const float* __restrict__ hprev, // 64x512 f32
                                                float* __restrict__ hnext,       // 64x512 f32
                                                u16* __restrict__ hbf_next,      // Abf + t*64*512
                                                float* __restrict__ hid_out) {
    int j0 = blockIdx.x * 64;
    __shared__ __align__(16) u16 Xs[64 * 32];
    __shared__ __align__(16) u16 Ws[3][64 * 32];
    int tid = threadIdx.x, lane = tid & 63, wid = tid >> 6;
    int wm = wid & 1, wn = wid >> 1;
    f32x4 acc[4][2][2] = {}; // 0:r(ih+hh) 1:z(ih+hh) 2:i_n 3:h_n
    for (int phase = 0; phase < 2; ++phase) {
        const u16* wsrc = phase ? whh : wih;
        int Ksz = phase ? 512 : 1024;
        int accN = phase ? 3 : 2;
        for (int k0 = 0; k0 < Ksz; k0 += 32) {
            {
                int c = tid;
                int r = c >> 2, c8 = (c & 3) * 8;
                int kk = k0 + c8;
                const u16* xsrc;
                if (phase == 0)
                    xsrc = (k0 < 512) ? (embbf_t + r * 512 + kk) : (ctxbf + r * 512 + kk - 512);
                else
                    xsrc = hbfp + r * 512 + kk;
                *(uint4*)&Xs[r * 32 + c8] = *(const uint4*)xsrc;
                for (int g = 0; g < 3; ++g) {
                    const u16* wp = wsrc + (size_t)(g * 512 + j0 + r) * Ksz + kk;
                    *(uint4*)&Ws[g][r * 32 + c8] = *(const uint4*)wp;
                }
            }
            __syncthreads();
            bf16x8 av[2], bvv[3][2];
            for (int mi = 0; mi < 2; ++mi)
                av[mi] = *(const bf16x8*)&Xs[(wm * 32 + mi * 16 + (lane & 15)) * 32 + (lane >> 4) * 8];
            for (int g = 0; g < 3; ++g)
                for (int ni = 0; ni < 2; ++ni)
                    bvv[g][ni] = *(const bf16x8*)&Ws[g][(wn * 32 + ni * 16 + (lane & 15)) * 32 + (lane >> 4) * 8];
            for (int mi = 0; mi < 2; ++mi)
                for (int ni = 0; ni < 2; ++ni) {
                    acc[0][mi][ni] = __builtin_amdgcn_mfma_f32_16x16x32_bf16(av[mi], bvv[0][ni], acc[0][mi][ni], 0, 0, 0);
                    acc[1][mi][ni] = __builtin_amdgcn_mfma_f32_16x16x32_bf16(av[mi], bvv[1][ni], acc[1][mi][ni], 0, 0, 0);
                    acc[accN][mi][ni] = __builtin_amdgcn_mfma_f32_16x16x32_bf16(av[mi], bvv[2][ni], acc[accN][mi][ni], 0, 0, 0);
                }
            __syncthreads();
        }
    }
    for (int mi = 0; mi < 2; ++mi)
        for (int ni = 0; ni < 2; ++ni) {
            int jj = wn * 32 + ni * 16 + (lane & 15);
            int j = j0 + jj;
            float bir = b_ih[j] + b_hh[j];
            float biz = b_ih[512 + j] + b_hh[512 + j];
            float bin = b_ih[1024 + j];
            float bhn = b_hh[1024 + j];
            for (int r = 0; r < 4; ++r) {
                int b = wm * 32 + mi * 16 + (lane >> 4) * 4 + r;
                float rg = 1.f / (1.f + __expf(-(acc[0][mi][ni][r] + bir)));
                float zg = 1.f / (1.f + __expf(-(acc[1][mi][ni][r] + biz)));
                float ng = tanhf(acc[2][mi][ni][r] + bin + rg * (acc[3][mi][ni][r] + bhn));
                float hp = hprev[(size_t)b * Hsz + j];
                float hv = (1.f - zg) * ng + zg * hp;
                hnext[(size_t)b * Hsz + j] = hv;
                hbf_next[(size_t)b * Hsz + j] = f2bf(hv);
                if (hid_out) hid_out[(size_t)b * Hsz + j] = hv;
            }
        }
}

// ---------------- log-softmax: pass 1 (row max + log-sum-exp) ----------------
__global__ __launch_bounds__(256) void lse_kernel(const float* __restrict__ out, float* __restrict__ lse) {
    int row = blockIdx.x;
    const float* p = out + (size_t)row * Vsz;
    __shared__ float red[256];
    int tid = threadIdx.x;
    float m = -1e30f;
    for (int v = tid; v < Vsz; v += 256) m = fmaxf(m, p[v]);
    red[tid] = m;
    __syncthreads();
    for (int s = 128; s; s >>= 1) {
        if (tid < s) red[tid] = fmaxf(red[tid], red[tid + s]);
        __syncthreads();
    }
    m = red[0];
    __syncthreads();
    float sum = 0.f;
    for (int v = tid; v < Vsz; v += 256) sum += __expf(p[v] - m);
    red[tid] = sum;
    __syncthreads();
    for (int s = 128; s; s >>= 1) {
        if (tid < s) red[tid] += red[tid + s];
        __syncthreads();
    }
    if (tid == 0) lse[row] = m + __logf(red[0]);
}

// ---------------- log-softmax: pass 2 (subtract, in place) ----------------
__global__ void sub_kernel(float* __restrict__ out, const float* __restrict__ lse) {
    const int total4 = (Bsz * Tsz * Vsz) / 4; // 16,384,000
    float4* o4 = (float4*)out;
    for (int i = blockIdx.x * blockDim.x + threadIdx.x; i < total4; i += gridDim.x * blockDim.x) {
        float l = lse[i / (Vsz / 4)];
        float4 v = o4[i];
        v.x -= l; v.y -= l; v.z -= l; v.w -= l;
        o4[i] = v;
    }
}

extern "C" void kernel_launch(void* const* d_in, const int* in_sizes, int n_in,
                              void* d_out, int out_size, void* d_ws, size_t ws_size,
                              hipStream_t stream) {
    const float* enc   = (const float*)d_in[0];
    const float* ehid  = (const float*)d_in[1];
    const int*   target= (const int*)d_in[2];
    const float* emb   = (const float*)d_in[3];
    const float* Wa    = (const float*)d_in[4];
    const float* ba    = (const float*)d_in[5];
    const float* Ua    = (const float*)d_in[6];
    const float* bu    = (const float*)d_in[7];
    const float* va    = (const float*)d_in[8];
    const float* bv    = (const float*)d_in[9];
    const float* w_ih  = (const float*)d_in[10];
    const float* b_ih  = (const float*)d_in[11];
    const float* w_hh  = (const float*)d_in[12];
    const float* b_hh  = (const float*)d_in[13];
    const float* Wo    = (const float*)d_in[14];
    const float* bo    = (const float*)d_in[15];
    float* out = (float*)d_out;

    const size_t HID_OFF = (size_t)Bsz * Tsz * Vsz;           // 65,536,000
    const size_t ATT_OFF = HID_OFF + (size_t)Bsz * Hsz;       // 65,568,768

    char* w = (char*)d_ws;
    float* uak  = (float*)w; w += (size_t)4096 * 512 * 4;
    float* hseq = (float*)w; w += (size_t)33 * Bsz * Hsz * 4;
    float* lse  = (float*)w; w += 2048 * 4;
    u16* embbf  = (u16*)w;   w += (size_t)Tsz * Bsz * Hsz * 2;
    u16* ctxbf  = (u16*)w;   w += (size_t)Bsz * Hsz * 2;
    u16* h0bf   = (u16*)w;   w += (size_t)Bsz * Hsz * 2;
    u16* Abf    = (u16*)w;   w += (size_t)2048 * 512 * 2;
    u16* encbf  = (u16*)w;   w += (size_t)4096 * 512 * 2;
    u16* Uabf   = (u16*)w;   w += (size_t)512 * 512 * 2;
    u16* wihbf  = (u16*)w;   w += (size_t)1536 * 1024 * 2;
    u16* whhbf  = (u16*)w;   w += (size_t)1536 * 512 * 2;
    u16* Wobf   = (u16*)w;   w += (size_t)Vsz * 512 * 2;

    // weight / input conversions
    convert_kernel<<<2048, 256, 0, stream>>>(enc, encbf, 4096 * 512);
    convert_kernel<<<512, 256, 0, stream>>>(Ua, Uabf, 512 * 512);
    convert_kernel<<<2048, 256, 0, stream>>>(w_ih, wihbf, 1536 * 1024);
    convert_kernel<<<1024, 256, 0, stream>>>(w_hh, whhbf, 1536 * 512);
    convert_kernel<<<4096, 256, 0, stream>>>(Wo, Wobf, Vsz * 512);
    embed_kernel<<<1024, 256, 0, stream>>>(target, emb, embbf);
    h0_kernel<<<128, 256, 0, stream>>>(ehid, hseq, h0bf);

    // Ua_keys = enc @ Ua.T + bu   (M=4096, N=512, K=512)
    gemm_bt<0><<<dim3(32, 4), 256, 0, stream>>>(encbf, Uabf, bu, uak, 4096, 512, 512);

    for (int t = 0; t < Tsz; ++t) {
        attn_step<<<64, 512, 0, stream>>>(hseq + (size_t)t * Bsz * Hsz, Wa, ba, uak, va, bv, enc,
                                          ctxbf, out + ATT_OFF, t);
        const u16* hbfp = (t == 0) ? h0bf : (Abf + (size_t)(t - 1) * Bsz * Hsz);
        gru_step<<<8, 256, 0, stream>>>(embbf + (size_t)t * Bsz * Hsz, ctxbf, hbfp, wihbf, whhbf,
                                        b_ih, b_hh,
                                        hseq + (size_t)t * Bsz * Hsz,
                                        hseq + (size_t)(t + 1) * Bsz * Hsz,
                                        Abf + (size_t)t * Bsz * Hsz,
                                        (t == Tsz - 1) ? (out + HID_OFF) : (float*)nullptr);
    }

    // logits = Hseq @ Wo.T + bo  (M=2048, N=32000, K=512) -> d_out (b,t,v) layout
    gemm_bt<1><<<dim3(16, 250), 256, 0, stream>>>(Abf, Wobf, bo, out, 2048, Vsz, 512);

    // log_softmax in place
    lse_kernel<<<2048, 256, 0, stream>>>(out, lse);
    sub_kernel<<<2048, 256, 0, stream>>>(out, lse);
}

// Round 2
// 2213.283 us; speedup vs baseline: 1.7267x; 1.7267x over previous
//
#include <hip/hip_runtime.h>

typedef unsigned short u16;
typedef __bf16 bf16x8 __attribute__((ext_vector_type(8)));
typedef float f32x4 __attribute__((ext_vector_type(4)));

#define Bsz 64
#define Ssz 64
#define Tsz 32
#define Hsz 512
#define Vsz 32000
#define NBLK 96

static __device__ inline u16 f2bf(float f) {
    union { float f; unsigned u; } v; v.f = f;
    unsigned u = v.u;
    unsigned r = (u + 0x7FFFu + ((u >> 16) & 1u)) >> 16;
    return (u16)r;
}
static __device__ inline float bf2f(u16 v) {
    union { unsigned u; float f; } x; x.u = ((unsigned)v) << 16; return x.f;
}
static __device__ inline float tanh_fast(float x) {
    float e = __expf(2.f * x);
    return 1.f - 2.f / (e + 1.f);
}

// ---------------- generic f32 -> bf16 convert ----------------
__global__ void convert_kernel(const float* __restrict__ src, u16* __restrict__ dst, int n) {
    for (int i = blockIdx.x * blockDim.x + threadIdx.x; i < n; i += gridDim.x * blockDim.x)
        dst[i] = f2bf(src[i]);
}

// ---------------- embedding gather into xbuf[t][b][0:512] (bf16) ----------------
__global__ void embed_kernel(const int* __restrict__ target, const float* __restrict__ emb,
                             u16* __restrict__ xbuf) {
    int n = Tsz * Bsz * Hsz;
    for (int i = blockIdx.x * blockDim.x + threadIdx.x; i < n; i += gridDim.x * blockDim.x) {
        int t = i / (Bsz * Hsz);
        int rem = i % (Bsz * Hsz);
        int b = rem / Hsz, k = rem % Hsz;
        int id = (t == 0) ? 0 : target[b * Tsz + (t - 1)];
        xbuf[((size_t)t * Bsz + b) * 1024 + k] = f2bf(emb[(size_t)id * Hsz + k]);
    }
}

__global__ void h0_kernel(const float* __restrict__ ehid, u16* __restrict__ h0bf) {
    int i = blockIdx.x * blockDim.x + threadIdx.x;
    if (i < Bsz * Hsz) h0bf[i] = f2bf(ehid[i]);
}

// ---------------- bf16 MFMA GEMM (unchanged from round 1) ----------------
template <int MODE>
__global__ __launch_bounds__(256) void gemm_bt(const u16* __restrict__ A, const u16* __restrict__ Bw,
                                               const float* __restrict__ bias, float* __restrict__ out,
                                               int M, int N, int K) {
    __shared__ __align__(16) u16 As[128 * 32];
    __shared__ __align__(16) u16 Bs[128 * 32];
    int m0 = blockIdx.x * 128, n0 = blockIdx.y * 128;
    int tid = threadIdx.x, lane = tid & 63, wid = tid >> 6;
    int wm = wid & 1, wn = wid >> 1;
    f32x4 acc[4][4] = {};
    for (int k0 = 0; k0 < K; k0 += 32) {
        for (int i = tid; i < 512; i += 256) {
            int r = i >> 2, c8 = (i & 3) * 8;
            *(uint4*)&As[r * 32 + c8] = *(const uint4*)&A[(size_t)(m0 + r) * K + k0 + c8];
            *(uint4*)&Bs[r * 32 + c8] = *(const uint4*)&Bw[(size_t)(n0 + r) * K + k0 + c8];
        }
        __syncthreads();
        bf16x8 av[4], bvv[4];
        for (int mi = 0; mi < 4; ++mi)
            av[mi] = *(const bf16x8*)&As[(wm * 64 + mi * 16 + (lane & 15)) * 32 + (lane >> 4) * 8];
        for (int ni = 0; ni < 4; ++ni)
            bvv[ni] = *(const bf16x8*)&Bs[(wn * 64 + ni * 16 + (lane & 15)) * 32 + (lane >> 4) * 8];
        for (int mi = 0; mi < 4; ++mi)
            for (int ni = 0; ni < 4; ++ni)
                acc[mi][ni] = __builtin_amdgcn_mfma_f32_16x16x32_bf16(av[mi], bvv[ni], acc[mi][ni], 0, 0, 0);
        __syncthreads();
    }
    for (int mi = 0; mi < 4; ++mi)
        for (int ni = 0; ni < 4; ++ni) {
            int n = n0 + wn * 64 + ni * 16 + (lane & 15);
            float bb = bias[n];
            for (int r = 0; r < 4; ++r) {
                int m = m0 + wm * 64 + mi * 16 + (lane >> 4) * 4 + r;
                float val = acc[mi][ni][r] + bb;
                if (MODE == 0)
                    out[(size_t)m * N + n] = val;
                else {
                    int t = m >> 6, b = m & 63;
                    out[((size_t)(b * Tsz + t)) * Vsz + n] = val;
                }
            }
        }
}

// ---------------- device-scope grid barrier ----------------
static __device__ inline void gridbar(unsigned* cnt, unsigned* gen) {
    __syncthreads();
    if (threadIdx.x == 0) {
        __threadfence();
        unsigned g = __hip_atomic_load(gen, __ATOMIC_RELAXED, __HIP_MEMORY_SCOPE_AGENT);
        unsigned arrived = __hip_atomic_fetch_add(cnt, 1u, __ATOMIC_ACQ_REL, __HIP_MEMORY_SCOPE_AGENT);
        if (arrived == NBLK - 1) {
            __hip_atomic_store(cnt, 0u, __ATOMIC_RELAXED, __HIP_MEMORY_SCOPE_AGENT);
            __hip_atomic_store(gen, g + 1u, __ATOMIC_RELEASE, __HIP_MEMORY_SCOPE_AGENT);
        } else {
            while (__hip_atomic_load(gen, __ATOMIC_ACQUIRE, __HIP_MEMORY_SCOPE_AGENT) == g) {}
        }
        __threadfence();
    }
    __syncthreads();
}

// ---------------- persistent recurrence kernel ----------------
// blocks 0..63  : "B-blocks" — batch b; uak[b] + enc[b] staged bf16 in LDS
// blocks 64..95 : "G-blocks" — 16-col slice; GRU weights staged (swizzled) in LDS,
//                 h kept in f32 registers across all 32 steps.
__global__ __launch_bounds__(512, 1) void coop_kernel(
    const float* __restrict__ uak, float* __restrict__ Whbuf,
    u16* __restrict__ xbuf, u16* __restrict__ Abf,
    const u16* __restrict__ h0bf, const u16* __restrict__ wihbf, const u16* __restrict__ whhbf,
    const u16* __restrict__ Wabf, const float* __restrict__ enc,
    const float* __restrict__ va, const float* __restrict__ bv, const float* __restrict__ ba,
    const float* __restrict__ b_ih, const float* __restrict__ b_hh,
    const float* __restrict__ ehid, float* __restrict__ out,
    unsigned* __restrict__ bar) {
    __shared__ __align__(16) char lds[147456];
    __shared__ float WhL[512];
    __shared__ float scL[64];
    __shared__ float vaL[512];

    unsigned* cnt = bar;
    unsigned* gen = bar + 1;

    const size_t HID_OFF = (size_t)Bsz * Tsz * Vsz;
    const size_t ATT_OFF = HID_OFF + (size_t)Bsz * Hsz;

    int tid = threadIdx.x, lane = tid & 63, wid = tid >> 6;
    int ln15 = lane & 15, hi = lane >> 4;
    int bx = blockIdx.x;
    bool isB = bx < 64;
    int g = bx - 64, jbase = g * 16;

    float hp0 = 0.f, hp1 = 0.f, hp2 = 0.f, hp3 = 0.f; // f32 hidden state (G, waves 0-3)
    float bir = 0.f, biz = 0.f, bin = 0.f, bhn = 0.f, ba_j = 0.f;

    if (isB) {
        int b = bx;
        u16* uakL = (u16*)lds;
        u16* encL = (u16*)(lds + 65536);
        for (int i = tid; i < Ssz * Hsz; i += 512) {
            uakL[i] = f2bf(uak[(size_t)b * Ssz * Hsz + i]);
            encL[i] = f2bf(enc[(size_t)b * Ssz * Hsz + i]);
        }
        vaL[tid] = va[tid];
    } else {
        // wih slice: 48 rows x 1024, row-swizzled (byte ^= (row&7)<<4) for conflict-free ds_read_b128
        for (int i = tid; i < 6144; i += 512) {
            int row = i >> 7, c16 = i & 127;
            int Rg = (row >> 4) * 512 + jbase + (row & 15);
            uint4 v = *(const uint4*)&wihbf[(size_t)Rg * 1024 + c16 * 8];
            *(uint4*)(lds + row * 2048 + ((c16 * 16) ^ ((row & 7) << 4))) = v;
        }
        // whh slice: 48 rows x 512
        for (int i = tid; i < 3072; i += 512) {
            int row = i >> 6, c16 = i & 63;
            int Rg = (row >> 4) * 512 + jbase + (row & 15);
            uint4 v = *(const uint4*)&whhbf[(size_t)Rg * 512 + c16 * 8];
            *(uint4*)(lds + 98304 + row * 1024 + ((c16 * 16) ^ ((row & 7) << 4))) = v;
        }
        int j = jbase + ln15;
        ba_j = ba[j];
        bir = b_ih[j] + b_hh[j];
        biz = b_ih[512 + j] + b_hh[512 + j];
        bin = b_ih[1024 + j];
        bhn = b_hh[1024 + j];
        if (wid < 4) {
            int m = wid;
            hp0 = ehid[(size_t)(m * 16 + hi * 4 + 0) * Hsz + j];
            hp1 = ehid[(size_t)(m * 16 + hi * 4 + 1) * Hsz + j];
            hp2 = ehid[(size_t)(m * 16 + hi * 4 + 2) * Hsz + j];
            hp3 = ehid[(size_t)(m * 16 + hi * 4 + 3) * Hsz + j];
        }
    }
    __syncthreads();

    for (int t = 0; t < Tsz; ++t) {
        const u16* hbt = (t == 0) ? h0bf : (Abf + (size_t)(t - 1) * Bsz * Hsz);
        // ---- Phase A: Wh = h_t(bf16) @ Wa^T + ba  (G-blocks, waves 0-3; wave = m-tile) ----
        if (!isB && wid < 4) {
            int m = wid;
            f32x4 acc = {};
#pragma unroll
            for (int k0 = 0; k0 < 16; ++k0) {
                bf16x8 a = *(const bf16x8*)&hbt[(size_t)(m * 16 + ln15) * 512 + k0 * 32 + hi * 8];
                bf16x8 bw = *(const bf16x8*)&Wabf[(size_t)(jbase + ln15) * 512 + k0 * 32 + hi * 8];
                acc = __builtin_amdgcn_mfma_f32_16x16x32_bf16(a, bw, acc, 0, 0, 0);
            }
            int j = jbase + ln15;
#pragma unroll
            for (int r = 0; r < 4; ++r)
                Whbuf[(size_t)(m * 16 + hi * 4 + r) * 512 + j] = acc[r] + ba_j;
        }
        gridbar(cnt, gen);
        // ---- Phase B: scores -> softmax -> ctx  (B-blocks, block = batch) ----
        if (isB) {
            int b = bx;
            const u16* uakL = (const u16*)lds;
            const u16* encL = (const u16*)(lds + 65536);
            WhL[tid] = Whbuf[(size_t)b * 512 + tid];
            __syncthreads();
            float bvv = bv[0];
            for (int si = 0; si < 8; ++si) {
                int s = wid * 8 + si;
                float a = 0.f;
#pragma unroll
                for (int ji = 0; ji < 8; ++ji) {
                    int j = lane + ji * 64;
                    float x = WhL[j] + bf2f(uakL[s * 512 + j]);
                    a += tanh_fast(x) * vaL[j];
                }
                for (int off = 32; off; off >>= 1) a += __shfl_down(a, off);
                if (lane == 0) scL[s] = a + bvv;
            }
            __syncthreads();
            if (wid == 0) {
                float x = scL[lane];
                float mx = x;
                for (int off = 32; off; off >>= 1) mx = fmaxf(mx, __shfl_xor(mx, off));
                float e = __expf(x - mx);
                float sm = e;
                for (int off = 32; off; off >>= 1) sm += __shfl_xor(sm, off);
                float at = e / sm;
                scL[lane] = at;
                out[ATT_OFF + ((size_t)b * Tsz + t) * Ssz + lane] = at;
            }
            __syncthreads();
            float c = 0.f;
            for (int s = 0; s < Ssz; ++s)
                c += scL[s] * bf2f(encL[s * 512 + tid]);
            xbuf[((size_t)t * Bsz + b) * 1024 + 512 + tid] = f2bf(c);
        }
        gridbar(cnt, gen);
        // ---- Phase C: GRU  (G-blocks, waves 0-3; wave = m-tile, 16 cols) ----
        if (!isB && wid < 4) {
            int m = wid;
            const char* wih_l = lds;
            const char* whh_l = lds + 98304;
            int swz = (ln15 & 7) << 4;
            f32x4 ar = {}, az = {}, ain = {}, ahn = {};
#pragma unroll 8
            for (int k0 = 0; k0 < 32; ++k0) {
                bf16x8 a = *(const bf16x8*)&xbuf[((size_t)t * Bsz + m * 16 + ln15) * 1024 + k0 * 32 + hi * 8];
                int byteIn = k0 * 64 + hi * 16;
                bf16x8 b0 = *(const bf16x8*)(wih_l + (0 + ln15) * 2048 + (byteIn ^ swz));
                bf16x8 b1 = *(const bf16x8*)(wih_l + (16 + ln15) * 2048 + (byteIn ^ swz));
                bf16x8 b2 = *(const bf16x8*)(wih_l + (32 + ln15) * 2048 + (byteIn ^ swz));
                ar = __builtin_amdgcn_mfma_f32_16x16x32_bf16(a, b0, ar, 0, 0, 0);
                az = __builtin_amdgcn_mfma_f32_16x16x32_bf16(a, b1, az, 0, 0, 0);
                ain = __builtin_amdgcn_mfma_f32_16x16x32_bf16(a, b2, ain, 0, 0, 0);
            }
#pragma unroll 8
            for (int k0 = 0; k0 < 16; ++k0) {
                bf16x8 a = *(const bf16x8*)&hbt[(size_t)(m * 16 + ln15) * 512 + k0 * 32 + hi * 8];
                int byteIn = k0 * 64 + hi * 16;
                bf16x8 b0 = *(const bf16x8*)(whh_l + (0 + ln15) * 1024 + (byteIn ^ swz));
                bf16x8 b1 = *(const bf16x8*)(whh_l + (16 + ln15) * 1024 + (byteIn ^ swz));
                bf16x8 b2 = *(const bf16x8*)(whh_l + (32 + ln15) * 1024 + (byteIn ^ swz));
                ar = __builtin_amdgcn_mfma_f32_16x16x32_bf16(a, b0, ar, 0, 0, 0);
                az = __builtin_amdgcn_mfma_f32_16x16x32_bf16(a, b1, az, 0, 0, 0);
                ahn = __builtin_amdgcn_mfma_f32_16x16x32_bf16(a, b2, ahn, 0, 0, 0);
            }
            int j = jbase + ln15;
            float hpv[4] = {hp0, hp1, hp2, hp3};
#pragma unroll
            for (int r = 0; r < 4; ++r) {
                int b = m * 16 + hi * 4 + r;
                float rg = 1.f / (1.f + __expf(-(ar[r] + bir)));
                float zg = 1.f / (1.f + __expf(-(az[r] + biz)));
                float ng = tanh_fast(ain[r] + bin + rg * (ahn[r] + bhn));
                float hv = (1.f - zg) * ng + zg * hpv[r];
                hpv[r] = hv;
                Abf[((size_t)t * Bsz + b) * 512 + j] = f2bf(hv);
                if (t == Tsz - 1) out[HID_OFF + (size_t)b * 512 + j] = hv;
            }
            hp0 = hpv[0]; hp1 = hpv[1]; hp2 = hpv[2]; hp3 = hpv[3];
        }
        gridbar(cnt, gen);
    }
}

// ---------------- log-softmax ----------------
__global__ __launch_bounds__(256) void lse_kernel(const float* __restrict__ out, float* __restrict__ lse) {
    int row = blockIdx.x;
    const float* p = out + (size_t)row * Vsz;
    __shared__ float red[256];
    int tid = threadIdx.x;
    float m = -1e30f;
    for (int v = tid; v < Vsz; v += 256) m = fmaxf(m, p[v]);
    red[tid] = m;
    __syncthreads();
    for (int s = 128; s; s >>= 1) {
        if (tid < s) red[tid] = fmaxf(red[tid], red[tid + s]);
        __syncthreads();
    }
    m = red[0];
    __syncthreads();
    float sum = 0.f;
    for (int v = tid; v < Vsz; v += 256) sum += __expf(p[v] - m);
    red[tid] = sum;
    __syncthreads();
    for (int s = 128; s; s >>= 1) {
        if (tid < s) red[tid] += red[tid + s];
        __syncthreads();
    }
    if (tid == 0) lse[row] = m + __logf(red[0]);
}

__global__ void sub_kernel(float* __restrict__ out, const float* __restrict__ lse) {
    const int total4 = (Bsz * Tsz * Vsz) / 4;
    float4* o4 = (float4*)out;
    for (int i = blockIdx.x * blockDim.x + threadIdx.x; i < total4; i += gridDim.x * blockDim.x) {
        float l = lse[i / (Vsz / 4)];
        float4 v = o4[i];
        v.x -= l; v.y -= l; v.z -= l; v.w -= l;
        o4[i] = v;
    }
}

extern "C" void kernel_launch(void* const* d_in, const int* in_sizes, int n_in,
                              void* d_out, int out_size, void* d_ws, size_t ws_size,
                              hipStream_t stream) {
    const float* enc   = (const float*)d_in[0];
    const float* ehid  = (const float*)d_in[1];
    const int*   target= (const int*)d_in[2];
    const float* emb   = (const float*)d_in[3];
    const float* Wa    = (const float*)d_in[4];
    const float* ba    = (const float*)d_in[5];
    const float* Ua    = (const float*)d_in[6];
    const float* bu    = (const float*)d_in[7];
    const float* va    = (const float*)d_in[8];
    const float* bv    = (const float*)d_in[9];
    const float* w_ih  = (const float*)d_in[10];
    const float* b_ih  = (const float*)d_in[11];
    const float* w_hh  = (const float*)d_in[12];
    const float* b_hh  = (const float*)d_in[13];
    const float* Wo    = (const float*)d_in[14];
    const float* bo    = (const float*)d_in[15];
    float* out = (float*)d_out;

    char* w = (char*)d_ws;
    float* uak   = (float*)w; w += (size_t)4096 * 512 * 4;       // 8 MB
    float* Whbuf = (float*)w; w += (size_t)Bsz * Hsz * 4;        // 128 KB
    float* lse   = (float*)w; w += 8192;
    unsigned* bar= (unsigned*)w; w += 64;
    u16* xbuf    = (u16*)w;   w += (size_t)Tsz * Bsz * 1024 * 2; // 4 MB
    u16* Abf     = (u16*)w;   w += (size_t)Tsz * Bsz * Hsz * 2;  // 2 MB
    u16* h0bf    = (u16*)w;   w += (size_t)Bsz * Hsz * 2;
    u16* Wabf    = (u16*)w;   w += (size_t)Hsz * Hsz * 2;
    u16* encbf   = (u16*)w;   w += (size_t)4096 * 512 * 2;
    u16* Uabf    = (u16*)w;   w += (size_t)Hsz * Hsz * 2;
    u16* wihbf   = (u16*)w;   w += (size_t)1536 * 1024 * 2;
    u16* whhbf   = (u16*)w;   w += (size_t)1536 * 512 * 2;
    u16* Wobf    = (u16*)w;   w += (size_t)Vsz * 512 * 2;

    convert_kernel<<<2048, 256, 0, stream>>>(enc, encbf, 4096 * 512);
    convert_kernel<<<512, 256, 0, stream>>>(Ua, Uabf, 512 * 512);
    convert_kernel<<<512, 256, 0, stream>>>(Wa, Wabf, 512 * 512);
    convert_kernel<<<2048, 256, 0, stream>>>(w_ih, wihbf, 1536 * 1024);
    convert_kernel<<<1024, 256, 0, stream>>>(w_hh, whhbf, 1536 * 512);
    convert_kernel<<<4096, 256, 0, stream>>>(Wo, Wobf, Vsz * 512);
    embed_kernel<<<1024, 256, 0, stream>>>(target, emb, xbuf);
    h0_kernel<<<128, 256, 0, stream>>>(ehid, h0bf);

    // Ua_keys = enc @ Ua.T + bu   (M=4096, N=512, K=512)
    gemm_bt<0><<<dim3(32, 4), 256, 0, stream>>>(encbf, Uabf, bu, uak, 4096, 512, 512);

    hipMemsetAsync(bar, 0, 8, stream);

    coop_kernel<<<NBLK, 512, 0, stream>>>(uak, Whbuf, xbuf, Abf, h0bf, wihbf, whhbf,
                                          Wabf, enc, va, bv, ba, b_ih, b_hh, ehid, out, bar);

    // logits = H @ Wo.T + bo  (M=2048, N=32000, K=512) -> (b,t,v)
    gemm_bt<1><<<dim3(16, 250), 256, 0, stream>>>(Abf, Wobf, bo, out, 2048, Vsz, 512);

    lse_kernel<<<2048, 256, 0, stream>>>(out, lse);
    sub_kernel<<<2048, 256, 0, stream>>>(out, lse);
}

// Round 3
// 1353.153 us; speedup vs baseline: 2.8242x; 1.6356x over previous
//
#include <hip/hip_runtime.h>

typedef unsigned short u16;
typedef __bf16 bf16x8 __attribute__((ext_vector_type(8)));
typedef float f32x4 __attribute__((ext_vector_type(4)));

#define Bsz 64
#define Ssz 64
#define Tsz 32
#define Hsz 512
#define Vsz 32000
#define NBLK 96

static __device__ inline u16 f2bf(float f) {
    union { float f; unsigned u; } v; v.f = f;
    unsigned u = v.u;
    unsigned r = (u + 0x7FFFu + ((u >> 16) & 1u)) >> 16;
    return (u16)r;
}
static __device__ inline float bf2f(u16 v) {
    union { unsigned u; float f; } x; x.u = ((unsigned)v) << 16; return x.f;
}
static __device__ inline float tanh_fast(float x) {
    float e = __expf(2.f * x);
    return 1.f - 2.f / (e + 1.f);
}
// agent-scope write-through stores (sc1) — reach the IC coherence point, no fences
static __device__ inline void st_f32(float* p, float v) {
    __hip_atomic_store(p, v, __ATOMIC_RELAXED, __HIP_MEMORY_SCOPE_AGENT);
}
static __device__ inline void st_u32(unsigned* p, unsigned v) {
    __hip_atomic_store(p, v, __ATOMIC_RELAXED, __HIP_MEMORY_SCOPE_AGENT);
}

// ---------------- generic f32 -> bf16 convert ----------------
__global__ void convert_kernel(const float* __restrict__ src, u16* __restrict__ dst, int n) {
    for (int i = blockIdx.x * blockDim.x + threadIdx.x; i < n; i += gridDim.x * blockDim.x)
        dst[i] = f2bf(src[i]);
}

// ---------------- embedding gather into xbuf[t][b][0:512] (bf16) ----------------
__global__ void embed_kernel(const int* __restrict__ target, const float* __restrict__ emb,
                             u16* __restrict__ xbuf) {
    int n = Tsz * Bsz * Hsz;
    for (int i = blockIdx.x * blockDim.x + threadIdx.x; i < n; i += gridDim.x * blockDim.x) {
        int t = i / (Bsz * Hsz);
        int rem = i % (Bsz * Hsz);
        int b = rem / Hsz, k = rem % Hsz;
        int id = (t == 0) ? 0 : target[b * Tsz + (t - 1)];
        xbuf[((size_t)t * Bsz + b) * 1024 + k] = f2bf(emb[(size_t)id * Hsz + k]);
    }
}

__global__ void h0_kernel(const float* __restrict__ ehid, u16* __restrict__ h0bf) {
    int i = blockIdx.x * blockDim.x + threadIdx.x;
    if (i < Bsz * Hsz) h0bf[i] = f2bf(ehid[i]);
}

// ---------------- bf16 MFMA GEMM:  C[m][n] = sum_k A[m][k]*Bw[n][k] + bias[n] ----------------
// MODE 0: out[m*N+n]      (Ua_keys)
// MODE 1: out[((m&63)*T + (m>>6))*V + n]  + per-row sum(exp) atomically into sumexp
template <int MODE>
__global__ __launch_bounds__(256) void gemm_bt(const u16* __restrict__ A, const u16* __restrict__ Bw,
                                               const float* __restrict__ bias, float* __restrict__ out,
                                               float* __restrict__ sumexp,
                                               int M, int N, int K) {
    __shared__ __align__(16) u16 As[128 * 32];
    __shared__ __align__(16) u16 Bs[128 * 32];
    int m0 = blockIdx.x * 128, n0 = blockIdx.y * 128;
    int tid = threadIdx.x, lane = tid & 63, wid = tid >> 6;
    int wm = wid & 1, wn = wid >> 1;
    f32x4 acc[4][4] = {};
    for (int k0 = 0; k0 < K; k0 += 32) {
        for (int i = tid; i < 512; i += 256) {
            int r = i >> 2, c8 = (i & 3) * 8;
            *(uint4*)&As[r * 32 + c8] = *(const uint4*)&A[(size_t)(m0 + r) * K + k0 + c8];
            *(uint4*)&Bs[r * 32 + c8] = *(const uint4*)&Bw[(size_t)(n0 + r) * K + k0 + c8];
        }
        __syncthreads();
        bf16x8 av[4], bvv[4];
        for (int mi = 0; mi < 4; ++mi)
            av[mi] = *(const bf16x8*)&As[(wm * 64 + mi * 16 + (lane & 15)) * 32 + (lane >> 4) * 8];
        for (int ni = 0; ni < 4; ++ni)
            bvv[ni] = *(const bf16x8*)&Bs[(wn * 64 + ni * 16 + (lane & 15)) * 32 + (lane >> 4) * 8];
        for (int mi = 0; mi < 4; ++mi)
            for (int ni = 0; ni < 4; ++ni)
                acc[mi][ni] = __builtin_amdgcn_mfma_f32_16x16x32_bf16(av[mi], bvv[ni], acc[mi][ni], 0, 0, 0);
        __syncthreads();
    }
    float rowpart[4][4];
    if (MODE == 1)
        for (int mi = 0; mi < 4; ++mi)
            for (int r = 0; r < 4; ++r) rowpart[mi][r] = 0.f;
    for (int mi = 0; mi < 4; ++mi)
        for (int ni = 0; ni < 4; ++ni) {
            int n = n0 + wn * 64 + ni * 16 + (lane & 15);
            float bb = bias[n];
            for (int r = 0; r < 4; ++r) {
                int m = m0 + wm * 64 + mi * 16 + (lane >> 4) * 4 + r;
                float val = acc[mi][ni][r] + bb;
                if (MODE == 0)
                    out[(size_t)m * N + n] = val;
                else {
                    int t = m >> 6, b = m & 63;
                    out[((size_t)(b * Tsz + t)) * Vsz + n] = val;
                    rowpart[mi][r] += __expf(val);
                }
            }
        }
    if (MODE == 1) {
        for (int mi = 0; mi < 4; ++mi)
            for (int r = 0; r < 4; ++r) {
                float v = rowpart[mi][r];
                v += __shfl_xor(v, 1);
                v += __shfl_xor(v, 2);
                v += __shfl_xor(v, 4);
                v += __shfl_xor(v, 8);
                if ((lane & 15) == 0) {
                    int m = m0 + wm * 64 + mi * 16 + (lane >> 4) * 4 + r;
                    int rowp = (m & 63) * Tsz + (m >> 6);
                    atomicAdd(&sumexp[rowp], v);
                }
            }
    }
}

// ---------------- fence-free device-scope grid barrier ----------------
// monotonic arrive counter + generation flag; RELAXED agent atomics only.
// Data visibility: all cross-block data is written with sc1 write-through atomic
// stores, drained by the vmcnt(0) the compiler emits before s_barrier in
// __syncthreads(); readers use normal loads on write-once-per-launch addresses.
static __device__ inline void gridbar(unsigned* cnt, unsigned* gen, unsigned kplus1) {
    __syncthreads();
    if (threadIdx.x == 0) {
        unsigned a = __hip_atomic_fetch_add(cnt, 1u, __ATOMIC_RELAXED, __HIP_MEMORY_SCOPE_AGENT);
        if (a == kplus1 * NBLK - 1u) {
            __hip_atomic_store(gen, kplus1, __ATOMIC_RELAXED, __HIP_MEMORY_SCOPE_AGENT);
        } else {
            while (__hip_atomic_load(gen, __ATOMIC_RELAXED, __HIP_MEMORY_SCOPE_AGENT) < kplus1) {}
        }
    }
    __syncthreads();
}

// ---------------- persistent recurrence kernel ----------------
// blocks 0..63  : "B-blocks" — batch b; uak[b] + enc[b] staged bf16 in LDS
// blocks 64..95 : "G-blocks" — 16-col slice; GRU weights staged (swizzled) in LDS,
//                 h kept in f32 registers across all 32 steps.
__global__ __launch_bounds__(512, 1) void coop_kernel(
    const float* __restrict__ uak, float* __restrict__ Whbuf,
    u16* __restrict__ xbuf, u16* __restrict__ Abf,
    const u16* __restrict__ h0bf, const u16* __restrict__ wihbf, const u16* __restrict__ whhbf,
    const u16* __restrict__ Wabf, const float* __restrict__ enc,
    const float* __restrict__ va, const float* __restrict__ bv, const float* __restrict__ ba,
    const float* __restrict__ b_ih, const float* __restrict__ b_hh,
    const float* __restrict__ ehid, float* __restrict__ out,
    unsigned* __restrict__ bar) {
    __shared__ __align__(16) char lds[147456];
    __shared__ float WhL[512];
    __shared__ float scL[64];
    __shared__ float vaL[512];

    unsigned* cnt = bar;
    unsigned* gen = bar + 1;
    unsigned bidx = 0;

    const size_t HID_OFF = (size_t)Bsz * Tsz * Vsz;
    const size_t ATT_OFF = HID_OFF + (size_t)Bsz * Hsz;

    int tid = threadIdx.x, lane = tid & 63, wid = tid >> 6;
    int ln15 = lane & 15, hi = lane >> 4;
    int bx = blockIdx.x;
    bool isB = bx < 64;
    int g = bx - 64, jbase = g * 16;

    unsigned* xbufU = (unsigned*)xbuf;
    unsigned* AbfU = (unsigned*)Abf;

    float hp0 = 0.f, hp1 = 0.f, hp2 = 0.f, hp3 = 0.f;
    float bir = 0.f, biz = 0.f, bin = 0.f, bhn = 0.f, ba_j = 0.f;

    if (isB) {
        int b = bx;
        u16* uakL = (u16*)lds;
        u16* encL = (u16*)(lds + 65536);
        for (int i = tid; i < Ssz * Hsz; i += 512) {
            uakL[i] = f2bf(uak[(size_t)b * Ssz * Hsz + i]);
            encL[i] = f2bf(enc[(size_t)b * Ssz * Hsz + i]);
        }
        vaL[tid] = va[tid];
    } else {
        for (int i = tid; i < 6144; i += 512) {
            int row = i >> 7, c16 = i & 127;
            int Rg = (row >> 4) * 512 + jbase + (row & 15);
            uint4 v = *(const uint4*)&wihbf[(size_t)Rg * 1024 + c16 * 8];
            *(uint4*)(lds + row * 2048 + ((c16 * 16) ^ ((row & 7) << 4))) = v;
        }
        for (int i = tid; i < 3072; i += 512) {
            int row = i >> 6, c16 = i & 63;
            int Rg = (row >> 4) * 512 + jbase + (row & 15);
            uint4 v = *(const uint4*)&whhbf[(size_t)Rg * 512 + c16 * 8];
            *(uint4*)(lds + 98304 + row * 1024 + ((c16 * 16) ^ ((row & 7) << 4))) = v;
        }
        int j = jbase + ln15;
        ba_j = ba[j];
        bir = b_ih[j] + b_hh[j];
        biz = b_ih[512 + j] + b_hh[512 + j];
        bin = b_ih[1024 + j];
        bhn = b_hh[1024 + j];
        if (wid < 4) {
            int m = wid;
            hp0 = ehid[(size_t)(m * 16 + hi * 4 + 0) * Hsz + j];
            hp1 = ehid[(size_t)(m * 16 + hi * 4 + 1) * Hsz + j];
            hp2 = ehid[(size_t)(m * 16 + hi * 4 + 2) * Hsz + j];
            hp3 = ehid[(size_t)(m * 16 + hi * 4 + 3) * Hsz + j];
        }
    }
    __syncthreads();

    for (int t = 0; t < Tsz; ++t) {
        const u16* hbt = (t == 0) ? h0bf : (Abf + (size_t)(t - 1) * Bsz * Hsz);
        float* Whb = Whbuf + (size_t)t * Bsz * Hsz;
        // ---- Phase A: Wh = h_t(bf16) @ Wa^T + ba  (G-blocks, waves 0-3) ----
        if (!isB && wid < 4) {
            int m = wid;
            f32x4 acc = {};
#pragma unroll
            for (int k0 = 0; k0 < 16; ++k0) {
                bf16x8 a = *(const bf16x8*)&hbt[(size_t)(m * 16 + ln15) * 512 + k0 * 32 + hi * 8];
                bf16x8 bw = *(const bf16x8*)&Wabf[(size_t)(jbase + ln15) * 512 + k0 * 32 + hi * 8];
                acc = __builtin_amdgcn_mfma_f32_16x16x32_bf16(a, bw, acc, 0, 0, 0);
            }
            int j = jbase + ln15;
#pragma unroll
            for (int r = 0; r < 4; ++r)
                st_f32(&Whb[(size_t)(m * 16 + hi * 4 + r) * 512 + j], acc[r] + ba_j);
        }
        gridbar(cnt, gen, ++bidx);
        // ---- Phase B: scores -> softmax -> ctx  (B-blocks) ----
        if (isB) {
            int b = bx;
            const u16* uakL = (const u16*)lds;
            const u16* encL = (const u16*)(lds + 65536);
            WhL[tid] = Whb[(size_t)b * 512 + tid];
            __syncthreads();
            float bvv = bv[0];
            for (int si = 0; si < 8; ++si) {
                int s = wid * 8 + si;
                float a = 0.f;
#pragma unroll
                for (int ji = 0; ji < 8; ++ji) {
                    int j = lane + ji * 64;
                    float x = WhL[j] + bf2f(uakL[s * 512 + j]);
                    a += tanh_fast(x) * vaL[j];
                }
                for (int off = 32; off; off >>= 1) a += __shfl_down(a, off);
                if (lane == 0) scL[s] = a + bvv;
            }
            __syncthreads();
            if (wid == 0) {
                float x = scL[lane];
                float mx = x;
                for (int off = 32; off; off >>= 1) mx = fmaxf(mx, __shfl_xor(mx, off));
                float e = __expf(x - mx);
                float sm = e;
                for (int off = 32; off; off >>= 1) sm += __shfl_xor(sm, off);
                float at = e / sm;
                scL[lane] = at;
                out[ATT_OFF + ((size_t)b * Tsz + t) * Ssz + lane] = at;
            }
            __syncthreads();
            float c = 0.f;
            for (int s = 0; s < Ssz; ++s)
                c += scL[s] * bf2f(encL[s * 512 + tid]);
            // packed write-through store of 2 bf16
            unsigned me = (unsigned)f2bf(c);
            unsigned other = __shfl_xor(me, 1);
            if ((tid & 1) == 0)
                st_u32(&xbufU[((size_t)t * Bsz + b) * 512 + 256 + (tid >> 1)], me | (other << 16));
        }
        gridbar(cnt, gen, ++bidx);
        // ---- Phase C: GRU  (G-blocks, waves 0-3) ----
        if (!isB && wid < 4) {
            int m = wid;
            const char* wih_l = lds;
            const char* whh_l = lds + 98304;
            int swz = (ln15 & 7) << 4;
            f32x4 ar = {}, az = {}, ain = {}, ahn = {};
#pragma unroll 8
            for (int k0 = 0; k0 < 32; ++k0) {
                bf16x8 a = *(const bf16x8*)&xbuf[((size_t)t * Bsz + m * 16 + ln15) * 1024 + k0 * 32 + hi * 8];
                int byteIn = k0 * 64 + hi * 16;
                bf16x8 b0 = *(const bf16x8*)(wih_l + (0 + ln15) * 2048 + (byteIn ^ swz));
                bf16x8 b1 = *(const bf16x8*)(wih_l + (16 + ln15) * 2048 + (byteIn ^ swz));
                bf16x8 b2 = *(const bf16x8*)(wih_l + (32 + ln15) * 2048 + (byteIn ^ swz));
                ar = __builtin_amdgcn_mfma_f32_16x16x32_bf16(a, b0, ar, 0, 0, 0);
                az = __builtin_amdgcn_mfma_f32_16x16x32_bf16(a, b1, az, 0, 0, 0);
                ain = __builtin_amdgcn_mfma_f32_16x16x32_bf16(a, b2, ain, 0, 0, 0);
            }
#pragma unroll 8
            for (int k0 = 0; k0 < 16; ++k0) {
                bf16x8 a = *(const bf16x8*)&hbt[(size_t)(m * 16 + ln15) * 512 + k0 * 32 + hi * 8];
                int byteIn = k0 * 64 + hi * 16;
                bf16x8 b0 = *(const bf16x8*)(whh_l + (0 + ln15) * 1024 + (byteIn ^ swz));
                bf16x8 b1 = *(const bf16x8*)(whh_l + (16 + ln15) * 1024 + (byteIn ^ swz));
                bf16x8 b2 = *(const bf16x8*)(whh_l + (32 + ln15) * 1024 + (byteIn ^ swz));
                ar = __builtin_amdgcn_mfma_f32_16x16x32_bf16(a, b0, ar, 0, 0, 0);
                az = __builtin_amdgcn_mfma_f32_16x16x32_bf16(a, b1, az, 0, 0, 0);
                ahn = __builtin_amdgcn_mfma_f32_16x16x32_bf16(a, b2, ahn, 0, 0, 0);
            }
            int j = jbase + ln15;
            float hpv[4] = {hp0, hp1, hp2, hp3};
#pragma unroll
            for (int r = 0; r < 4; ++r) {
                int b = m * 16 + hi * 4 + r;
                float rg = 1.f / (1.f + __expf(-(ar[r] + bir)));
                float zg = 1.f / (1.f + __expf(-(az[r] + biz)));
                float ng = tanh_fast(ain[r] + bin + rg * (ahn[r] + bhn));
                float hv = (1.f - zg) * ng + zg * hpv[r];
                hpv[r] = hv;
                // packed write-through store of 2 bf16 (lanes ln15 even/odd pair)
                unsigned me = (unsigned)f2bf(hv);
                unsigned other = __shfl_xor(me, 1);
                if ((ln15 & 1) == 0)
                    st_u32(&AbfU[((size_t)t * Bsz + b) * 256 + (j >> 1)], me | (other << 16));
                if (t == Tsz - 1) out[HID_OFF + (size_t)b * 512 + j] = hv;
            }
            hp0 = hpv[0]; hp1 = hpv[1]; hp2 = hpv[2]; hp3 = hpv[3];
        }
        gridbar(cnt, gen, ++bidx);
    }
}

// ---------------- log-softmax subtract (uses fused sumexp) ----------------
__global__ void sub_kernel(float* __restrict__ out, const float* __restrict__ sumexp) {
    const int total4 = (Bsz * Tsz * Vsz) / 4;
    float4* o4 = (float4*)out;
    for (int i = blockIdx.x * blockDim.x + threadIdx.x; i < total4; i += gridDim.x * blockDim.x) {
        float l = __logf(sumexp[i / (Vsz / 4)]);
        float4 v = o4[i];
        v.x -= l; v.y -= l; v.z -= l; v.w -= l;
        o4[i] = v;
    }
}

extern "C" void kernel_launch(void* const* d_in, const int* in_sizes, int n_in,
                              void* d_out, int out_size, void* d_ws, size_t ws_size,
                              hipStream_t stream) {
    const float* enc   = (const float*)d_in[0];
    const float* ehid  = (const float*)d_in[1];
    const int*   target= (const int*)d_in[2];
    const float* emb   = (const float*)d_in[3];
    const float* Wa    = (const float*)d_in[4];
    const float* ba    = (const float*)d_in[5];
    const float* Ua    = (const float*)d_in[6];
    const float* bu    = (const float*)d_in[7];
    const float* va    = (const float*)d_in[8];
    const float* bv    = (const float*)d_in[9];
    const float* w_ih  = (const float*)d_in[10];
    const float* b_ih  = (const float*)d_in[11];
    const float* w_hh  = (const float*)d_in[12];
    const float* b_hh  = (const float*)d_in[13];
    const float* Wo    = (const float*)d_in[14];
    const float* bo    = (const float*)d_in[15];
    float* out = (float*)d_out;

    char* w = (char*)d_ws;
    float* uak   = (float*)w; w += (size_t)4096 * 512 * 4;            // 8 MB
    float* Whbuf = (float*)w; w += (size_t)Tsz * Bsz * Hsz * 4;       // 4 MB (per-step)
    float* sumexp= (float*)w; w += 8192;
    unsigned* bar= (unsigned*)w; w += 64;
    u16* xbuf    = (u16*)w;   w += (size_t)Tsz * Bsz * 1024 * 2;      // 4 MB
    u16* Abf     = (u16*)w;   w += (size_t)Tsz * Bsz * Hsz * 2;       // 2 MB
    u16* h0bf    = (u16*)w;   w += (size_t)Bsz * Hsz * 2;
    u16* Wabf    = (u16*)w;   w += (size_t)Hsz * Hsz * 2;
    u16* encbf   = (u16*)w;   w += (size_t)4096 * 512 * 2;
    u16* Uabf    = (u16*)w;   w += (size_t)Hsz * Hsz * 2;
    u16* wihbf   = (u16*)w;   w += (size_t)1536 * 1024 * 2;
    u16* whhbf   = (u16*)w;   w += (size_t)1536 * 512 * 2;
    u16* Wobf    = (u16*)w;   w += (size_t)Vsz * 512 * 2;

    convert_kernel<<<2048, 256, 0, stream>>>(enc, encbf, 4096 * 512);
    convert_kernel<<<512, 256, 0, stream>>>(Ua, Uabf, 512 * 512);
    convert_kernel<<<512, 256, 0, stream>>>(Wa, Wabf, 512 * 512);
    convert_kernel<<<2048, 256, 0, stream>>>(w_ih, wihbf, 1536 * 1024);
    convert_kernel<<<1024, 256, 0, stream>>>(w_hh, whhbf, 1536 * 512);
    convert_kernel<<<4096, 256, 0, stream>>>(Wo, Wobf, Vsz * 512);
    embed_kernel<<<1024, 256, 0, stream>>>(target, emb, xbuf);
    h0_kernel<<<128, 256, 0, stream>>>(ehid, h0bf);

    // Ua_keys = enc @ Ua.T + bu   (M=4096, N=512, K=512)
    gemm_bt<0><<<dim3(32, 4), 256, 0, stream>>>(encbf, Uabf, bu, uak, (float*)nullptr, 4096, 512, 512);

    hipMemsetAsync(bar, 0, 8, stream);
    hipMemsetAsync(sumexp, 0, 2048 * 4, stream);

    coop_kernel<<<NBLK, 512, 0, stream>>>(uak, Whbuf, xbuf, Abf, h0bf, wihbf, whhbf,
                                          Wabf, enc, va, bv, ba, b_ih, b_hh, ehid, out, bar);

    // logits = H @ Wo.T + bo  (M=2048, N=32000, K=512) -> (b,t,v) + fused sum(exp)
    gemm_bt<1><<<dim3(16, 250), 256, 0, stream>>>(Abf, Wobf, bo, out, sumexp, 2048, Vsz, 512);

    sub_kernel<<<2048, 256, 0, stream>>>(out, sumexp);
}

// Round 5
// 969.299 us; speedup vs baseline: 3.9427x; 1.3960x over previous
//
#include <hip/hip_runtime.h>

typedef unsigned short u16;
typedef __bf16 bf16x8 __attribute__((ext_vector_type(8)));
typedef float f32x4 __attribute__((ext_vector_type(4)));

#define Bsz 64
#define Ssz 64
#define Tsz 32
#define Hsz 512
#define Vsz 32000
#define NBLK 96

static __device__ inline u16 f2bf(float f) {
    union { float f; unsigned u; } v; v.f = f;
    unsigned u = v.u;
    unsigned r = (u + 0x7FFFu + ((u >> 16) & 1u)) >> 16;
    return (u16)r;
}
static __device__ inline float bf2f(u16 v) {
    union { unsigned u; float f; } x; x.u = ((unsigned)v) << 16; return x.f;
}
static __device__ inline float tanh_fast(float x) {
    float e = __expf(2.f * x);
    return 1.f - 2.f / (e + 1.f);
}
// agent-scope write-through stores (sc1) — reach the IC coherence point
static __device__ inline void st_f32(float* p, float v) {
    __hip_atomic_store(p, v, __ATOMIC_RELAXED, __HIP_MEMORY_SCOPE_AGENT);
}
static __device__ inline void st_u32(unsigned* p, unsigned v) {
    __hip_atomic_store(p, v, __ATOMIC_RELAXED, __HIP_MEMORY_SCOPE_AGENT);
}

// direct-to-LDS 16B async copy (wave-uniform LDS base + lane*16 scatter)
#define GLOAD_LDS16(g, l) \
    __builtin_amdgcn_global_load_lds((const __attribute__((address_space(1))) void*)(g), \
                                     (__attribute__((address_space(3))) void*)(l), 16, 0, 0)

// ---------------- fused f32 -> bf16 weight prep ----------------
__global__ void prep_kernel(const float* __restrict__ enc, const float* __restrict__ Ua,
                            const float* __restrict__ Wa, const float* __restrict__ wih,
                            const float* __restrict__ whh, const float* __restrict__ Wo,
                            const float* __restrict__ ehid,
                            u16* __restrict__ encbf, u16* __restrict__ Uabf,
                            u16* __restrict__ Wabf, u16* __restrict__ wihbf,
                            u16* __restrict__ whhbf, u16* __restrict__ Wobf,
                            u16* __restrict__ h0bf) {
    const int n0 = 2097152, n1 = 262144, n2 = 262144, n3 = 1572864, n4 = 786432, n5 = 16384000, n6 = 32768;
    const int total = n0 + n1 + n2 + n3 + n4 + n5 + n6;
    for (int i = blockIdx.x * blockDim.x + threadIdx.x; i < total; i += gridDim.x * blockDim.x) {
        int j = i;
        if (j < n0) { encbf[j] = f2bf(enc[j]); continue; } j -= n0;
        if (j < n1) { Uabf[j] = f2bf(Ua[j]); continue; } j -= n1;
        if (j < n2) { Wabf[j] = f2bf(Wa[j]); continue; } j -= n2;
        if (j < n3) { wihbf[j] = f2bf(wih[j]); continue; } j -= n3;
        if (j < n4) { whhbf[j] = f2bf(whh[j]); continue; } j -= n4;
        if (j < n5) { Wobf[j] = f2bf(Wo[j]); continue; } j -= n5;
        h0bf[j] = f2bf(ehid[j]);
    }
}

// ---------------- embedding gather into xbuf[t][b][0:512] (bf16) ----------------
__global__ void embed_kernel(const int* __restrict__ target, const float* __restrict__ emb,
                             u16* __restrict__ xbuf) {
    int n = Tsz * Bsz * Hsz;
    for (int i = blockIdx.x * blockDim.x + threadIdx.x; i < n; i += gridDim.x * blockDim.x) {
        int t = i / (Bsz * Hsz);
        int rem = i % (Bsz * Hsz);
        int b = rem / Hsz, k = rem % Hsz;
        int id = (t == 0) ? 0 : target[b * Tsz + (t - 1)];
        xbuf[((size_t)t * Bsz + b) * 1024 + k] = f2bf(emb[(size_t)id * Hsz + k]);
    }
}

// ---------------- bf16 MFMA GEMM:  C[m][n] = sum_k A[m][k]*Bw[n][k] + bias[n] ----------------
// MODE 0: out[m*N+n]      (Ua_keys)
// MODE 1: out[((m&63)*T + (m>>6))*V + n]  + per-row sum(exp) atomically into sumexp
template <int MODE>
__global__ __launch_bounds__(256) void gemm_bt(const u16* __restrict__ A, const u16* __restrict__ Bw,
                                               const float* __restrict__ bias, float* __restrict__ out,
                                               float* __restrict__ sumexp,
                                               int M, int N, int K) {
    __shared__ __align__(16) u16 As[128 * 32];
    __shared__ __align__(16) u16 Bs[128 * 32];
    int m0 = blockIdx.x * 128, n0 = blockIdx.y * 128;
    int tid = threadIdx.x, lane = tid & 63, wid = tid >> 6;
    int wm = wid & 1, wn = wid >> 1;
    f32x4 acc[4][4] = {};
    for (int k0 = 0; k0 < K; k0 += 32) {
        // direct global->LDS staging, 16B/lane (identical LDS image as the ds_write version)
        int e0 = wid * 64 + lane;
        int e1 = e0 + 256;
        GLOAD_LDS16(&A[(size_t)(m0 + (e0 >> 2)) * K + k0 + (e0 & 3) * 8], (char*)As + wid * 1024);
        GLOAD_LDS16(&A[(size_t)(m0 + (e1 >> 2)) * K + k0 + (e1 & 3) * 8], (char*)As + 4096 + wid * 1024);
        GLOAD_LDS16(&Bw[(size_t)(n0 + (e0 >> 2)) * K + k0 + (e0 & 3) * 8], (char*)Bs + wid * 1024);
        GLOAD_LDS16(&Bw[(size_t)(n0 + (e1 >> 2)) * K + k0 + (e1 & 3) * 8], (char*)Bs + 4096 + wid * 1024);
        __syncthreads();
        bf16x8 av[4], bvv[4];
        for (int mi = 0; mi < 4; ++mi)
            av[mi] = *(const bf16x8*)&As[(wm * 64 + mi * 16 + (lane & 15)) * 32 + (lane >> 4) * 8];
        for (int ni = 0; ni < 4; ++ni)
            bvv[ni] = *(const bf16x8*)&Bs[(wn * 64 + ni * 16 + (lane & 15)) * 32 + (lane >> 4) * 8];
        for (int mi = 0; mi < 4; ++mi)
            for (int ni = 0; ni < 4; ++ni)
                acc[mi][ni] = __builtin_amdgcn_mfma_f32_16x16x32_bf16(av[mi], bvv[ni], acc[mi][ni], 0, 0, 0);
        __syncthreads();
    }
    float rowpart[4][4];
    if (MODE == 1)
        for (int mi = 0; mi < 4; ++mi)
            for (int r = 0; r < 4; ++r) rowpart[mi][r] = 0.f;
    for (int mi = 0; mi < 4; ++mi)
        for (int ni = 0; ni < 4; ++ni) {
            int n = n0 + wn * 64 + ni * 16 + (lane & 15);
            float bb = bias[n];
            for (int r = 0; r < 4; ++r) {
                int m = m0 + wm * 64 + mi * 16 + (lane >> 4) * 4 + r;
                float val = acc[mi][ni][r] + bb;
                if (MODE == 0)
                    out[(size_t)m * N + n] = val;
                else {
                    int t = m >> 6, b = m & 63;
                    out[((size_t)(b * Tsz + t)) * Vsz + n] = val;
                    rowpart[mi][r] += __expf(val);
                }
            }
        }
    if (MODE == 1) {
        for (int mi = 0; mi < 4; ++mi)
            for (int r = 0; r < 4; ++r) {
                float v = rowpart[mi][r];
                v += __shfl_xor(v, 1);
                v += __shfl_xor(v, 2);
                v += __shfl_xor(v, 4);
                v += __shfl_xor(v, 8);
                if ((lane & 15) == 0) {
                    int m = m0 + wm * 64 + mi * 16 + (lane >> 4) * 4 + r;
                    int rowp = (m & 63) * Tsz + (m >> 6);
                    atomicAdd(&sumexp[rowp], v);
                }
            }
    }
}

// ---------------- flag-array sync (no RMW, no leader) ----------------
// Each block owns one 128B-spaced monotonic flag slot (slot = blockIdx.x).
// arrive: drain stores -> block barrier -> one lane writes step value.
// pollflags: lanes 0..n-1 each spin on one producer flag, then block barrier.
static __device__ inline void arrive(unsigned* bar, int slot, unsigned val, int tid) {
    asm volatile("s_waitcnt vmcnt(0)" ::: "memory");
    __syncthreads();
    if (tid == 0) st_u32(&bar[slot * 32], val);
}
static __device__ inline void pollflags(unsigned* bar, int base, int n, unsigned target, int tid) {
    if (tid < n) {
        unsigned* p = &bar[(base + tid) * 32];
        while (__hip_atomic_load(p, __ATOMIC_RELAXED, __HIP_MEMORY_SCOPE_AGENT) < target) {}
    }
    __syncthreads();
}

// ---------------- persistent recurrence kernel ----------------
// blocks 0..63  ("B"): batch b; uak[b] + enc[b] staged bf16 in LDS. attention.
// blocks 64..95 ("G"): 16-col slice; GRU weights LDS-resident (swizzled);
//                      h in f32 registers across all 32 steps. Wh-MFMA + GRU.
// Per step t (flag values): G arrives 3t+1 (Wh done) and 3t+3 (h_t done);
// B arrives 3t+2 (ctx done). B polls G>=3t+1; G polls G>=3t then B>=3t+2.
// G overlaps the wih*emb and whh*h halves of the GRU into B's window.
__global__ __launch_bounds__(512, 1) void coop_kernel(
    const float* __restrict__ uak, float* __restrict__ Whbuf,
    u16* __restrict__ xbuf, u16* __restrict__ Abf,
    const u16* __restrict__ h0bf, const u16* __restrict__ wihbf, const u16* __restrict__ whhbf,
    const u16* __restrict__ Wabf, const float* __restrict__ enc,
    const float* __restrict__ va, const float* __restrict__ bv, const float* __restrict__ ba,
    const float* __restrict__ b_ih, const float* __restrict__ b_hh,
    const float* __restrict__ ehid, float* __restrict__ out,
    unsigned* __restrict__ bar) {
    __shared__ __align__(16) char lds[147456];
    __shared__ float WhL[512];
    __shared__ float scL[64];
    __shared__ float vaL[512];

    const size_t HID_OFF = (size_t)Bsz * Tsz * Vsz;
    const size_t ATT_OFF = HID_OFF + (size_t)Bsz * Hsz;

    int tid = threadIdx.x, lane = tid & 63, wid = tid >> 6;
    int ln15 = lane & 15, hi = lane >> 4;
    int bx = blockIdx.x;
    bool isB = bx < 64;
    int g = bx - 64, jbase = g * 16;

    unsigned* xbufU = (unsigned*)xbuf;
    unsigned* AbfU = (unsigned*)Abf;

    if (isB) {
        // ================= B-blocks: attention =================
        int b = bx;
        u16* uakL = (u16*)lds;
        u16* encL = (u16*)(lds + 65536);
        for (int i = tid; i < Ssz * Hsz; i += 512) {
            uakL[i] = f2bf(uak[(size_t)b * Ssz * Hsz + i]);
            encL[i] = f2bf(enc[(size_t)b * Ssz * Hsz + i]);
        }
        vaL[tid] = va[tid];
        float bvv = bv[0];
        __syncthreads();

        for (int t = 0; t < Tsz; ++t) {
            pollflags(bar, 64, 32, 3u * t + 1u, tid);           // Wh ready
            WhL[tid] = Whbuf[(size_t)t * Bsz * Hsz + (size_t)b * 512 + tid];
            __syncthreads();
            for (int si = 0; si < 8; ++si) {
                int s = wid * 8 + si;
                float a = 0.f;
#pragma unroll
                for (int ji = 0; ji < 8; ++ji) {
                    int j = lane + ji * 64;
                    float x = WhL[j] + bf2f(uakL[s * 512 + j]);
                    a += tanh_fast(x) * vaL[j];
                }
                for (int off = 32; off; off >>= 1) a += __shfl_down(a, off);
                if (lane == 0) scL[s] = a + bvv;
            }
            __syncthreads();
            if (wid == 0) {
                float x = scL[lane];
                float mx = x;
                for (int off = 32; off; off >>= 1) mx = fmaxf(mx, __shfl_xor(mx, off));
                float e = __expf(x - mx);
                float sm = e;
                for (int off = 32; off; off >>= 1) sm += __shfl_xor(sm, off);
                float at = e / sm;
                scL[lane] = at;
                out[ATT_OFF + ((size_t)b * Tsz + t) * Ssz + lane] = at;
            }
            __syncthreads();
            float c = 0.f;
            for (int s = 0; s < Ssz; ++s)
                c += scL[s] * bf2f(encL[s * 512 + tid]);
            unsigned me = (unsigned)f2bf(c);
            unsigned other = __shfl_xor(me, 1);
            if ((tid & 1) == 0)
                st_u32(&xbufU[((size_t)t * Bsz + b) * 512 + 256 + (tid >> 1)], me | (other << 16));
            arrive(bar, bx, 3u * t + 2u, tid);                   // ctx ready
        }
    } else {
        // ================= G-blocks: Wh-MFMA + GRU =================
        for (int i = tid; i < 6144; i += 512) {
            int row = i >> 7, c16 = i & 127;
            int Rg = (row >> 4) * 512 + jbase + (row & 15);
            uint4 v = *(const uint4*)&wihbf[(size_t)Rg * 1024 + c16 * 8];
            *(uint4*)(lds + row * 2048 + ((c16 * 16) ^ ((row & 7) << 4))) = v;
        }
        for (int i = tid; i < 3072; i += 512) {
            int row = i >> 6, c16 = i & 63;
            int Rg = (row >> 4) * 512 + jbase + (row & 15);
            uint4 v = *(const uint4*)&whhbf[(size_t)Rg * 512 + c16 * 8];
            *(uint4*)(lds + 98304 + row * 1024 + ((c16 * 16) ^ ((row & 7) << 4))) = v;
        }
        const char* wih_l = lds;
        const char* whh_l = lds + 98304;
        int j = jbase + ln15;
        float ba_j = ba[j];
        float bir = b_ih[j] + b_hh[j];
        float biz = b_ih[512 + j] + b_hh[512 + j];
        float bin = b_ih[1024 + j];
        float bhn = b_hh[1024 + j];
        float hp0 = 0.f, hp1 = 0.f, hp2 = 0.f, hp3 = 0.f;
        if (wid < 4) {
            int m = wid;
            hp0 = ehid[(size_t)(m * 16 + hi * 4 + 0) * Hsz + j];
            hp1 = ehid[(size_t)(m * 16 + hi * 4 + 1) * Hsz + j];
            hp2 = ehid[(size_t)(m * 16 + hi * 4 + 2) * Hsz + j];
            hp3 = ehid[(size_t)(m * 16 + hi * 4 + 3) * Hsz + j];
        }
        int swz = (ln15 & 7) << 4;

        for (int t = 0; t < Tsz; ++t) {
            const u16* hbt = (t == 0) ? h0bf : (Abf + (size_t)(t - 1) * Bsz * Hsz);
            float* Whb = Whbuf + (size_t)t * Bsz * Hsz;
            pollflags(bar, 64, 32, 3u * t, tid);                 // all h_{t-1} written
            // ---- Wh = h_{t-1} @ Wa^T + ba ----
            if (wid < 4) {
                int m = wid;
                f32x4 acc = {};
#pragma unroll
                for (int k0 = 0; k0 < 16; ++k0) {
                    bf16x8 a = *(const bf16x8*)&hbt[(size_t)(m * 16 + ln15) * 512 + k0 * 32 + hi * 8];
                    bf16x8 bw = *(const bf16x8*)&Wabf[(size_t)(jbase + ln15) * 512 + k0 * 32 + hi * 8];
                    acc = __builtin_amdgcn_mfma_f32_16x16x32_bf16(a, bw, acc, 0, 0, 0);
                }
#pragma unroll
                for (int r = 0; r < 4; ++r)
                    st_f32(&Whb[(size_t)(m * 16 + hi * 4 + r) * 512 + j], acc[r] + ba_j);
            }
            arrive(bar, bx, 3u * t + 1u, tid);                   // Wh ready
            // ---- GRU prework (overlaps B's attention): wih*emb + whh*h ----
            f32x4 ar = {}, az = {}, ain = {}, ahn = {};
            if (wid < 4) {
                int m = wid;
#pragma unroll 8
                for (int k0 = 0; k0 < 16; ++k0) {
                    bf16x8 a = *(const bf16x8*)&xbuf[((size_t)t * Bsz + m * 16 + ln15) * 1024 + k0 * 32 + hi * 8];
                    int byteIn = k0 * 64 + hi * 16;
                    bf16x8 b0 = *(const bf16x8*)(wih_l + (0 + ln15) * 2048 + (byteIn ^ swz));
                    bf16x8 b1 = *(const bf16x8*)(wih_l + (16 + ln15) * 2048 + (byteIn ^ swz));
                    bf16x8 b2 = *(const bf16x8*)(wih_l + (32 + ln15) * 2048 + (byteIn ^ swz));
                    ar = __builtin_amdgcn_mfma_f32_16x16x32_bf16(a, b0, ar, 0, 0, 0);
                    az = __builtin_amdgcn_mfma_f32_16x16x32_bf16(a, b1, az, 0, 0, 0);
                    ain = __builtin_amdgcn_mfma_f32_16x16x32_bf16(a, b2, ain, 0, 0, 0);
                }
#pragma unroll 8
                for (int k0 = 0; k0 < 16; ++k0) {
                    bf16x8 a = *(const bf16x8*)&hbt[(size_t)(m * 16 + ln15) * 512 + k0 * 32 + hi * 8];
                    int byteIn = k0 * 64 + hi * 16;
                    bf16x8 b0 = *(const bf16x8*)(whh_l + (0 + ln15) * 1024 + (byteIn ^ swz));
                    bf16x8 b1 = *(const bf16x8*)(whh_l + (16 + ln15) * 1024 + (byteIn ^ swz));
                    bf16x8 b2 = *(const bf16x8*)(whh_l + (32 + ln15) * 1024 + (byteIn ^ swz));
                    ar = __builtin_amdgcn_mfma_f32_16x16x32_bf16(a, b0, ar, 0, 0, 0);
                    az = __builtin_amdgcn_mfma_f32_16x16x32_bf16(a, b1, az, 0, 0, 0);
                    ahn = __builtin_amdgcn_mfma_f32_16x16x32_bf16(a, b2, ahn, 0, 0, 0);
                }
            }
            pollflags(bar, 0, 64, 3u * t + 2u, tid);             // ctx ready
            // ---- GRU critical: wih*ctx + gates ----
            if (wid < 4) {
                int m = wid;
#pragma unroll 8
                for (int k0 = 16; k0 < 32; ++k0) {
                    bf16x8 a = *(const bf16x8*)&xbuf[((size_t)t * Bsz + m * 16 + ln15) * 1024 + k0 * 32 + hi * 8];
                    int byteIn = k0 * 64 + hi * 16;
                    bf16x8 b0 = *(const bf16x8*)(wih_l + (0 + ln15) * 2048 + (byteIn ^ swz));
                    bf16x8 b1 = *(const bf16x8*)(wih_l + (16 + ln15) * 2048 + (byteIn ^ swz));
                    bf16x8 b2 = *(const bf16x8*)(wih_l + (32 + ln15) * 2048 + (byteIn ^ swz));
                    ar = __builtin_amdgcn_mfma_f32_16x16x32_bf16(a, b0, ar, 0, 0, 0);
                    az = __builtin_amdgcn_mfma_f32_16x16x32_bf16(a, b1, az, 0, 0, 0);
                    ain = __builtin_amdgcn_mfma_f32_16x16x32_bf16(a, b2, ain, 0, 0, 0);
                }
                float hpv[4] = {hp0, hp1, hp2, hp3};
#pragma unroll
                for (int r = 0; r < 4; ++r) {
                    int b = m * 16 + hi * 4 + r;
                    float rg = 1.f / (1.f + __expf(-(ar[r] + bir)));
                    float zg = 1.f / (1.f + __expf(-(az[r] + biz)));
                    float ng = tanh_fast(ain[r] + bin + rg * (ahn[r] + bhn));
                    float hv = (1.f - zg) * ng + zg * hpv[r];
                    hpv[r] = hv;
                    unsigned me = (unsigned)f2bf(hv);
                    unsigned other = __shfl_xor(me, 1);
                    if ((ln15 & 1) == 0)
                        st_u32(&AbfU[((size_t)t * Bsz + b) * 256 + (j >> 1)], me | (other << 16));
                    if (t == Tsz - 1) out[HID_OFF + (size_t)b * 512 + j] = hv;
                }
                hp0 = hpv[0]; hp1 = hpv[1]; hp2 = hpv[2]; hp3 = hpv[3];
            }
            arrive(bar, bx, 3u * t + 3u, tid);                   // h_t ready
        }
    }
}

// ---------------- log-softmax subtract (uses fused sumexp) ----------------
__global__ void sub_kernel(float* __restrict__ out, const float* __restrict__ sumexp) {
    const int total4 = (Bsz * Tsz * Vsz) / 4;
    float4* o4 = (float4*)out;
    for (int i = blockIdx.x * blockDim.x + threadIdx.x; i < total4; i += gridDim.x * blockDim.x) {
        float l = __logf(sumexp[i / (Vsz / 4)]);
        float4 v = o4[i];
        v.x -= l; v.y -= l; v.z -= l; v.w -= l;
        o4[i] = v;
    }
}

extern "C" void kernel_launch(void* const* d_in, const int* in_sizes, int n_in,
                              void* d_out, int out_size, void* d_ws, size_t ws_size,
                              hipStream_t stream) {
    const float* enc   = (const float*)d_in[0];
    const float* ehid  = (const float*)d_in[1];
    const int*   target= (const int*)d_in[2];
    const float* emb   = (const float*)d_in[3];
    const float* Wa    = (const float*)d_in[4];
    const float* ba    = (const float*)d_in[5];
    const float* Ua    = (const float*)d_in[6];
    const float* bu    = (const float*)d_in[7];
    const float* va    = (const float*)d_in[8];
    const float* bv    = (const float*)d_in[9];
    const float* w_ih  = (const float*)d_in[10];
    const float* b_ih  = (const float*)d_in[11];
    const float* w_hh  = (const float*)d_in[12];
    const float* b_hh  = (const float*)d_in[13];
    const float* Wo    = (const float*)d_in[14];
    const float* bo    = (const float*)d_in[15];
    float* out = (float*)d_out;

    char* w = (char*)d_ws;
    float* uak   = (float*)w; w += (size_t)4096 * 512 * 4;            // 8 MB
    float* Whbuf = (float*)w; w += (size_t)Tsz * Bsz * Hsz * 4;       // 4 MB
    float* sumexp= (float*)w; w += 8192;
    unsigned* bar= (unsigned*)w; w += 96 * 128;                       // 96 x 128B flag slots
    u16* xbuf    = (u16*)w;   w += (size_t)Tsz * Bsz * 1024 * 2;      // 4 MB
    u16* Abf     = (u16*)w;   w += (size_t)Tsz * Bsz * Hsz * 2;       // 2 MB
    u16* h0bf    = (u16*)w;   w += (size_t)Bsz * Hsz * 2;
    u16* Wabf    = (u16*)w;   w += (size_t)Hsz * Hsz * 2;
    u16* encbf   = (u16*)w;   w += (size_t)4096 * 512 * 2;
    u16* Uabf    = (u16*)w;   w += (size_t)Hsz * Hsz * 2;
    u16* wihbf   = (u16*)w;   w += (size_t)1536 * 1024 * 2;
    u16* whhbf   = (u16*)w;   w += (size_t)1536 * 512 * 2;
    u16* Wobf    = (u16*)w;   w += (size_t)Vsz * 512 * 2;

    prep_kernel<<<2048, 256, 0, stream>>>(enc, Ua, Wa, w_ih, w_hh, Wo, ehid,
                                          encbf, Uabf, Wabf, wihbf, whhbf, Wobf, h0bf);
    embed_kernel<<<1024, 256, 0, stream>>>(target, emb, xbuf);

    // Ua_keys = enc @ Ua.T + bu   (M=4096, N=512, K=512)
    gemm_bt<0><<<dim3(32, 4), 256, 0, stream>>>(encbf, Uabf, bu, uak, (float*)nullptr, 4096, 512, 512);

    // bar region is 96 slots x 128 BYTES = 12288 bytes. Round 4 bug: memset of
    // 96*128*4 bytes overran into xbuf and wiped t=0 embeddings. Clear exactly it.
    hipMemsetAsync(bar, 0, 96 * 128, stream);
    hipMemsetAsync(sumexp, 0, 2048 * 4, stream);

    coop_kernel<<<NBLK, 512, 0, stream>>>(uak, Whbuf, xbuf, Abf, h0bf, wihbf, whhbf,
                                          Wabf, enc, va, bv, ba, b_ih, b_hh, ehid, out, bar);

    // logits = H @ Wo.T + bo  (M=2048, N=32000, K=512) -> (b,t,v) + fused sum(exp)
    gemm_bt<1><<<dim3(16, 250), 256, 0, stream>>>(Abf, Wobf, bo, out, sumexp, 2048, Vsz, 512);

    sub_kernel<<<2048, 256, 0, stream>>>(out, sumexp);
}